// Round 1
// baseline (227.243 us; speedup 1.0000x reference)
//
#include <hip/hip_runtime.h>
#include <math.h>

#define TPB 256

// Per-row contributor tables, derived from the reference's fixed scatter:
// tau_g = h2o_sq; tau_g[H2O_ROWS]+=h2o[H2O_IDX]; tau_g[O3_ROWS]+=o3; ...
// Net id spaces: h2o 0..22, h2o_sq 23..51, o3 52..64, co2 65..73,
//                n2o 74..76, ch4 77..85, u 86..98.
// Comp id: 0=h2o 1=h2o_sq 2=o3 3=co2 4=n2o 5=ch4 6=u.
static __device__ const int ROW_START[30] = {
    0, 7, 14, 21, 24, 27, 30, 33, 36, 39, 42, 45, 48, 51, 54, 57, 60,
    63, 67, 71, 75, 79, 83, 87, 88, 89, 91, 93, 96, 99};

static __device__ const unsigned char NET_ID[99] = {
    23, 0, 52, 65, 74, 77, 86,   // row 0
    24, 1, 53, 66, 75, 78, 87,   // row 1
    25, 2, 54, 67, 76, 79, 88,   // row 2
    26, 3, 80,                   // row 3
    27, 4, 81,                   // row 4
    28, 5, 68,                   // row 5
    29, 6, 69,                   // row 6
    30, 3, 82,                   // row 7 (h2o idx 3 reused)
    31, 4, 83,                   // row 8 (h2o idx 4 reused)
    32, 9, 70,                   // row 9
    33, 10, 71,                  // row 10
    34, 11, 84,                  // row 11
    35, 12, 85,                  // row 12
    36, 13, 72,                  // row 13
    37, 14, 73,                  // row 14
    38, 15, 89,                  // row 15
    39, 16, 90,                  // row 16
    40, 17, 55, 91,              // row 17
    41, 18, 56, 92,              // row 18
    42, 19, 57, 93,              // row 19
    43, 20, 58, 94,              // row 20
    44, 21, 59, 95,              // row 21
    45, 22, 60, 96,              // row 22
    46,                          // row 23
    47,                          // row 24
    48, 61,                      // row 25
    49, 62,                      // row 26
    50, 63, 97,                  // row 27
    51, 64, 98};                 // row 28

static __device__ const unsigned char COMP_ID[99] = {
    1, 0, 2, 3, 4, 5, 6,
    1, 0, 2, 3, 4, 5, 6,
    1, 0, 2, 3, 4, 5, 6,
    1, 0, 5,
    1, 0, 5,
    1, 0, 3,
    1, 0, 3,
    1, 0, 5,
    1, 0, 5,
    1, 0, 3,
    1, 0, 3,
    1, 0, 5,
    1, 0, 5,
    1, 0, 3,
    1, 0, 3,
    1, 0, 6,
    1, 0, 6,
    1, 0, 2, 6,
    1, 0, 2, 6,
    1, 0, 2, 6,
    1, 0, 2, 6,
    1, 0, 2, 6,
    1, 0, 2, 6,
    1,
    1,
    1, 2,
    1, 2,
    1, 2, 6,
    1, 2, 6};

__device__ __forceinline__ float fast_rcp(float x) {
    return __builtin_amdgcn_rcpf(x);
}

__global__ __launch_bounds__(TPB) void atm_kernel(
    const float* __restrict__ temp,
    const float* __restrict__ pressure,
    const float* __restrict__ c_h2o,
    const float* __restrict__ c_h2o_sq,
    const float* __restrict__ c_o3,
    const float* __restrict__ c_co2,
    const float* __restrict__ c_n2o,
    const float* __restrict__ c_ch4,
    const float* __restrict__ c_u,
    const float* __restrict__ lwp,
    const float* __restrict__ iwp,
    const float* __restrict__ mu,
    const float* __restrict__ mu_bar,
    const float* __restrict__ gW1,   // (99,2,8)
    const float* __restrict__ gb1,   // (99,8)
    const float* __restrict__ gW2,   // (99,8,1)
    const float* __restrict__ gb2,   // (99,1)
    const float* __restrict__ lw_w,  // (29,1)
    const float* __restrict__ iw_w,  // (29,1)
    const float* __restrict__ eW1,   // (29,4,16)
    const float* __restrict__ eb1,   // (29,16)
    const float* __restrict__ eW2,   // (29,16,3)
    const float* __restrict__ eb2,   // (29,3)
    float* __restrict__ out,
    int Bn)
{
    const int r = blockIdx.x;                       // wave-uniform row 0..28
    const int b = blockIdx.y * TPB + threadIdx.x;   // batch element
    if (b >= Bn) return;

    const float t = temp[b];
    const float p = pressure[b];
    float comp[7];
    comp[0] = c_h2o[b];
    comp[1] = c_h2o_sq[b];
    comp[2] = c_o3[b];
    comp[3] = c_co2[b];
    comp[4] = c_n2o[b];
    comp[5] = c_ch4[b];
    comp[6] = c_u[b];
    const float lwp_b = lwp[b], iwp_b = iwp[b];
    const float mu_b = mu[b], mub_b = mu_bar[b];

    // ---- gas nets contributing to this row ----
    float tau_g = 0.f;
    const int i0 = ROW_START[r], i1 = ROW_START[r + 1];
    for (int i = i0; i < i1; ++i) {
        const int n = NET_ID[i];
        const float* w1 = gW1 + n * 16;  // [0..7]=input0 weights, [8..15]=input1
        const float* b1 = gb1 + n * 8;
        const float* w2 = gW2 + n * 8;
        float acc = gb2[n];
        #pragma unroll
        for (int j = 0; j < 8; ++j) {
            float h = fmaf(t, w1[j], fmaf(p, w1[8 + j], b1[j]));
            h = h > 0.f ? h : (__expf(h) - 1.f);   // ELU
            acc = fmaf(h, w2[j], acc);
        }
        acc = fmaxf(acc, 0.f);                     // ReLU -> ke
        tau_g = fmaf(acc, comp[COMP_ID[i]], tau_g);
    }

    // ---- tau composition ----
    const float tlw = lw_w[r] * lwp_b;
    const float tiw = iw_w[r] * iwp_b;
    const float tau_tot = tau_g + tlw + tiw;       // > 0 always
    const float inv_tt = fast_rcp(tau_tot);
    const float in1 = tlw * inv_tt;
    const float in2 = tiw * inv_tt;
    const float in3_dir = tau_tot * fast_rcp(mu_b);
    const float in3_dif = tau_tot * fast_rcp(mub_b);

    const size_t idx = (size_t)r * (size_t)Bn + (size_t)b;
    out[idx] = __expf(-in3_dir);                       // t_direct
    out[(size_t)29 * Bn + idx] = __expf(-in3_dif);     // t_diffuse

    // ---- extinction net (row r), two passes: direct / diffuse ----
    const float* w1 = eW1 + r * 64;  // [i*16+j]
    const float* b1 = eb1 + r * 16;
    const float* w2 = eW2 + r * 48;  // [j*3+k]
    const float* b2 = eb2 + r * 3;

    float res[6];
    #pragma unroll
    for (int pass = 0; pass < 2; ++pass) {
        const float i3 = (pass == 0) ? in3_dir : in3_dif;
        const float m  = (pass == 0) ? mu_b : mub_b;
        float o0 = b2[0], o1 = b2[1], o2 = b2[2];
        #pragma unroll
        for (int j = 0; j < 16; ++j) {
            float h = fmaf(in1, w1[j], b1[j]);
            h = fmaf(in2, w1[16 + j], h);
            h = fmaf(i3,  w1[32 + j], h);
            h = fmaf(m,   w1[48 + j], h);
            h = h > 0.f ? h : (__expf(h) - 1.f);   // ELU
            o0 = fmaf(h, w2[3 * j + 0], o0);
            o1 = fmaf(h, w2[3 * j + 1], o1);
            o2 = fmaf(h, w2[3 * j + 2], o2);
        }
        o0 = fmaxf(o0, 0.f);
        o1 = fmaxf(o1, 0.f);
        o2 = fmaxf(o2, 0.f);
        // softmax over 3
        const float mx = fmaxf(o0, fmaxf(o1, o2));
        const float e0 = __expf(o0 - mx);
        const float e1 = __expf(o1 - mx);
        const float e2 = __expf(o2 - mx);
        const float rs = fast_rcp(e0 + e1 + e2);
        res[pass * 3 + 0] = e0 * rs;
        res[pass * 3 + 1] = e1 * rs;
        res[pass * 3 + 2] = e2 * rs;
    }

    float* pd = out + (size_t)58 * Bn + idx * 3;    // e_direct (29,B,3)
    pd[0] = res[0]; pd[1] = res[1]; pd[2] = res[2];
    float* pf = out + (size_t)145 * Bn + idx * 3;   // e_diffuse (29,B,3)
    pf[0] = res[3]; pf[1] = res[4]; pf[2] = res[5];
}

extern "C" void kernel_launch(void* const* d_in, const int* in_sizes, int n_in,
                              void* d_out, int out_size, void* d_ws, size_t ws_size,
                              hipStream_t stream) {
    const int Bn = in_sizes[0];  // temp has B elements
    dim3 grid(29, (Bn + TPB - 1) / TPB);
    atm_kernel<<<grid, TPB, 0, stream>>>(
        (const float*)d_in[0],  (const float*)d_in[1],  (const float*)d_in[2],
        (const float*)d_in[3],  (const float*)d_in[4],  (const float*)d_in[5],
        (const float*)d_in[6],  (const float*)d_in[7],  (const float*)d_in[8],
        (const float*)d_in[9],  (const float*)d_in[10], (const float*)d_in[11],
        (const float*)d_in[12], (const float*)d_in[13], (const float*)d_in[14],
        (const float*)d_in[15], (const float*)d_in[16], (const float*)d_in[17],
        (const float*)d_in[18], (const float*)d_in[19], (const float*)d_in[20],
        (const float*)d_in[21], (const float*)d_in[22],
        (float*)d_out, Bn);
}